// Round 1
// baseline (768.842 us; speedup 1.0000x reference)
//
#include <hip/hip_runtime.h>
#include <hip/hip_bf16.h>
#include <cstdint>

#define N_NODES 100000
#define N_EDGES 1600000
#define FDIM 64
#define NPAIRS 200000
#define CAP 64

__device__ __forceinline__ float rlf(float v, int lane) {
    return __int_as_float(__builtin_amdgcn_readlane(__float_as_int(v), lane));
}

// K0: h0 = 2*x (self term: (1+eps)*x + x inside agg), deg = 0
__global__ void k0_init(const float4* __restrict__ x4, float4* __restrict__ h04,
                        int* __restrict__ deg) {
    int i = blockIdx.x * blockDim.x + threadIdx.x;
    if (i < N_NODES * FDIM / 4) {
        float4 v = x4[i];
        v.x *= 2.f; v.y *= 2.f; v.z *= 2.f; v.w *= 2.f;
        h04[i] = v;
    }
    if (i < N_NODES) deg[i] = 0;
}

// K1: bucket edges by dst. Overflow (deg > CAP, prob ~2e-13 total but must be
// correct) falls back to direct atomics into h0 (initialized by K0).
__global__ void k1_fill(const int* __restrict__ src, const int* __restrict__ dst,
                        const float* __restrict__ x, float* __restrict__ h0,
                        int* __restrict__ deg, int* __restrict__ slots) {
    int e = blockIdx.x * blockDim.x + threadIdx.x;
    if (e >= N_EDGES) return;
    int s = src[e], d = dst[e];
    int pos = atomicAdd(&deg[d], 1);
    if (pos < CAP) {
        slots[(size_t)d * CAP + pos] = s;
    } else {
        const float* xr = x + (size_t)s * FDIM;
        float* hr = h0 + (size_t)d * FDIM;
        for (int f = 0; f < FDIM; ++f) atomicAdd(&hr[f], xr[f]);
    }
}

// K2: per-node gather-sum. Wave per node, lane = feature. Slot row preloaded
// coalesced into one VGPR per lane, broadcast via readlane.
__global__ void __launch_bounds__(256) k2_agg(const float* __restrict__ x,
                       float* __restrict__ h0,
                       const int* __restrict__ deg, const int* __restrict__ slots) {
    int tid = threadIdx.x;
    int lane = tid & 63;
    int n = blockIdx.x * 4 + (tid >> 6);
    float acc = h0[(size_t)n * FDIM + lane];
    int dc = deg[n];
    if (dc > CAP) dc = CAP;
    int sl = slots[(size_t)n * CAP + lane];  // full row, lane i = slot i
    for (int i = 0; i < dc; ++i) {
        int s = __builtin_amdgcn_readlane(sl, i);
        acc += x[(size_t)s * FDIM + lane];
    }
    h0[(size_t)n * FDIM + lane] = acc;
}

// K3: node MLP, in-place h0 -> h. Wave per node, lane = output unit.
// Row broadcast via readlane (VALU), weights in LDS.
__global__ void __launch_bounds__(256) k3_mlp(float* __restrict__ h,
                       const float* __restrict__ w1, const float* __restrict__ b1,
                       const float* __restrict__ w2, const float* __restrict__ b2) {
    __shared__ float w1s[64 * 64];
    __shared__ float w2s[64 * 64];
    int tid = threadIdx.x;
    const float4* w14 = (const float4*)w1;
    const float4* w24 = (const float4*)w2;
    float4* w1s4 = (float4*)w1s;
    float4* w2s4 = (float4*)w2s;
    for (int i = tid; i < 64 * 64 / 4; i += 256) {
        w1s4[i] = w14[i];
        w2s4[i] = w24[i];
    }
    __syncthreads();
    int lane = tid & 63;
    int n = blockIdx.x * 4 + (tid >> 6);
    float b1r = b1[lane], b2r = b2[lane];
    float v = h[(size_t)n * 64 + lane];
    float acc = b1r;
#pragma unroll
    for (int k = 0; k < 64; ++k) acc = fmaf(rlf(v, k), w1s[k * 64 + lane], acc);
    float t = fmaxf(acc, 0.f);
    float acc2 = b2r;
#pragma unroll
    for (int k = 0; k < 64; ++k) acc2 = fmaf(rlf(t, k), w2s[k * 64 + lane], acc2);
    h[(size_t)n * 64 + lane] = fmaxf(acc2, 0.f);
}

// K4: pair decoder. Wave per pair; dw1 (256x64 f32 = 64KB) in LDS; lane = d1
// unit j; e1/e2 broadcast via readlane; 2 readlanes feed 4 FMAs (the 4 feat
// sections all derive from (e1[k], e2[k])).
__global__ void __launch_bounds__(256) k4_pair(const float* __restrict__ h,
                        const int* __restrict__ qidx,
                        const float* __restrict__ dw1, const float* __restrict__ db1,
                        const float* __restrict__ dw2, const float* __restrict__ db2,
                        float* __restrict__ out, int numWaves) {
    __shared__ float W[256 * 64];  // 64 KB -> 2 blocks/CU
    int tid = threadIdx.x;
    const float4* dw14 = (const float4*)dw1;
    float4* W4 = (float4*)W;
    for (int i = tid; i < 256 * 64 / 4; i += 256) W4[i] = dw14[i];
    __syncthreads();
    int lane = tid & 63;
    float db1r = db1[lane];
    float dw2r = dw2[lane];
    float db2r = db2[0];
    int wid = (blockIdx.x * 256 + tid) >> 6;
    for (int p = wid; p < NPAIRS; p += numWaves) {
        int i1 = qidx[p];
        int i2 = qidx[NPAIRS + p];
        float e1 = h[(size_t)i1 * 64 + lane];
        float e2 = h[(size_t)i2 * 64 + lane];
        float acc = db1r;
#pragma unroll
        for (int k = 0; k < 64; ++k) {
            float a = rlf(e1, k);
            float b = rlf(e2, k);
            acc = fmaf(a + b, W[k * 64 + lane], acc);           // e1+e2 section
            acc = fmaf(a * b, W[(64 + k) * 64 + lane], acc);    // e1*e2 section
            acc = fmaf(a,     W[(128 + k) * 64 + lane], acc);   // e1 section
            acc = fmaf(b,     W[(192 + k) * 64 + lane], acc);   // e2 section
        }
        float r = fmaxf(acc, 0.f) * dw2r;
#pragma unroll
        for (int off = 32; off >= 1; off >>= 1) r += __shfl_xor(r, off, 64);
        if (lane == 0) out[p] = r + db2r;
    }
}

extern "C" void kernel_launch(void* const* d_in, const int* in_sizes, int n_in,
                              void* d_out, int out_size, void* d_ws, size_t ws_size,
                              hipStream_t stream) {
    const float* x    = (const float*)d_in[0];   // [N,64]
    const int*   eidx = (const int*)d_in[1];     // [2,E]: src = eidx, dst = eidx+E
    // d_in[2] = curvature: unused by the reference output
    const int*   qidx = (const int*)d_in[3];     // [2,P]
    const float* w1   = (const float*)d_in[4];
    const float* b1   = (const float*)d_in[5];
    const float* w2   = (const float*)d_in[6];
    const float* b2   = (const float*)d_in[7];
    const float* dw1  = (const float*)d_in[8];   // [256,64]
    const float* db1  = (const float*)d_in[9];
    const float* dw2  = (const float*)d_in[10];  // [64]
    const float* db2  = (const float*)d_in[11];  // [1]
    float* out = (float*)d_out;                  // [P]

    // Workspace layout (ws re-poisoned 0xAA each call; we init what we read):
    //   h0    : N*64 f32   = 25,600,000 B   (becomes h in-place after k3)
    //   deg   : N   i32    =    400,000 B
    //   slots : N*CAP i32  = 25,600,000 B
    char* ws = (char*)d_ws;
    float* h0   = (float*)ws;
    int*   deg  = (int*)(ws + (size_t)N_NODES * FDIM * 4);
    int*   slots = (int*)(ws + (size_t)N_NODES * FDIM * 4 + (size_t)N_NODES * 4);

    const int* src = eidx;
    const int* dst = eidx + N_EDGES;

    // K0: 6250*256 = 1,600,000 = N*64/4 exactly
    k0_init<<<6250, 256, 0, stream>>>((const float4*)x, (float4*)h0, deg);
    // K1: 6250*256 = E exactly
    k1_fill<<<6250, 256, 0, stream>>>(src, dst, x, h0, deg, slots);
    // K2/K3: 4 nodes per block, 25000*4 = N exactly
    k2_agg<<<25000, 256, 0, stream>>>(x, h0, deg, slots);
    k3_mlp<<<25000, 256, 0, stream>>>(h0, w1, b1, w2, b2);
    // K4: 1024 blocks * 4 waves = 4096 waves, grid-stride over P
    const int blocks4 = 1024;
    k4_pair<<<blocks4, 256, 0, stream>>>(h0, qidx, dw1, db1, dw2, db2, out,
                                         blocks4 * 4);
}

// Round 2
// 573.106 us; speedup vs baseline: 1.3415x; 1.3415x over previous
//
#include <hip/hip_runtime.h>
#include <hip/hip_bf16.h>
#include <cstdint>

#define N_NODES 100000
#define N_EDGES 1600000
#define FDIM 64
#define NPAIRS 200000
#define CAP 64

__device__ __forceinline__ float rlf(float v, int lane) {
    return __int_as_float(__builtin_amdgcn_readlane(__float_as_int(v), lane));
}

// K0: h0 = 2*x (self term: (1+eps)*x + x inside agg), deg = 0
__global__ void k0_init(const float4* __restrict__ x4, float4* __restrict__ h04,
                        int* __restrict__ deg) {
    int i = blockIdx.x * blockDim.x + threadIdx.x;
    if (i < N_NODES * FDIM / 4) {
        float4 v = x4[i];
        v.x *= 2.f; v.y *= 2.f; v.z *= 2.f; v.w *= 2.f;
        h04[i] = v;
    }
    if (i < N_NODES) deg[i] = 0;
}

// K1: bucket edges by dst. Overflow (deg > CAP, prob ~2e-13 total but must be
// correct) falls back to direct atomics into h0 (initialized by K0).
__global__ void k1_fill(const int* __restrict__ src, const int* __restrict__ dst,
                        const float* __restrict__ x, float* __restrict__ h0,
                        int* __restrict__ deg, int* __restrict__ slots) {
    int e = blockIdx.x * blockDim.x + threadIdx.x;
    if (e >= N_EDGES) return;
    int s = src[e], d = dst[e];
    int pos = atomicAdd(&deg[d], 1);
    if (pos < CAP) {
        slots[(size_t)d * CAP + pos] = s;
    } else {
        const float* xr = x + (size_t)s * FDIM;
        float* hr = h0 + (size_t)d * FDIM;
        for (int f = 0; f < FDIM; ++f) atomicAdd(&hr[f], xr[f]);
    }
}

// K2: per-node gather-sum, float4 rows, 4 neighbors per wave-iteration.
// lane = nb*16 + fq: neighbor-slot nb in [0,4), float4-chunk fq in [0,16).
// Each iteration issues 4 row-gathers of 1 KB total; final cross-group
// reduction via shfl_xor(16,32).
__global__ void __launch_bounds__(256) k2_agg(const float4* __restrict__ x4,
                       float4* __restrict__ h04,
                       const int* __restrict__ deg, const int* __restrict__ slots) {
    int tid = threadIdx.x;
    int lane = tid & 63;
    int n = blockIdx.x * 4 + (tid >> 6);
    int nb = lane >> 4;
    int fq = lane & 15;
    int dc = deg[n];
    if (dc > CAP) dc = CAP;
    int sl = slots[n * CAP + lane];  // lane i holds slot i of this node's row
    float4 acc = {0.f, 0.f, 0.f, 0.f};
    for (int i = 0; i < dc; i += 4) {
        int si = i + nb;
        int s = __shfl(sl, si, 64);   // divergent index -> bpermute
        if (si < dc) {
            float4 v = x4[(size_t)s * 16 + fq];
            acc.x += v.x; acc.y += v.y; acc.z += v.z; acc.w += v.w;
        }
    }
#pragma unroll
    for (int off = 16; off <= 32; off <<= 1) {
        acc.x += __shfl_xor(acc.x, off, 64);
        acc.y += __shfl_xor(acc.y, off, 64);
        acc.z += __shfl_xor(acc.z, off, 64);
        acc.w += __shfl_xor(acc.w, off, 64);
    }
    if (nb == 0) {
        float4 self = h04[(size_t)n * 16 + fq];  // 2x (+ any overflow atomics)
        self.x += acc.x; self.y += acc.y; self.z += acc.z; self.w += acc.w;
        h04[(size_t)n * 16 + fq] = self;
    }
}

// K3: node MLP, in-place, 8 nodes per wave. lane = output unit; one
// ds_read_b32 of w[k][lane] serves 8 nodes (8 readlane + 8 FMA).
__global__ void __launch_bounds__(256) k3_mlp(float* __restrict__ h,
                       const float* __restrict__ w1, const float* __restrict__ b1,
                       const float* __restrict__ w2, const float* __restrict__ b2) {
    __shared__ float w1s[64 * 64];
    __shared__ float w2s[64 * 64];
    int tid = threadIdx.x;
    const float4* w14 = (const float4*)w1;
    const float4* w24 = (const float4*)w2;
    float4* w1s4 = (float4*)w1s;
    float4* w2s4 = (float4*)w2s;
    for (int i = tid; i < 64 * 64 / 4; i += 256) {
        w1s4[i] = w14[i];
        w2s4[i] = w24[i];
    }
    __syncthreads();
    int lane = tid & 63;
    int wid = blockIdx.x * 4 + (tid >> 6);   // wave task id, 12500 total
    int n0 = wid * 8;
    float b1r = b1[lane], b2r = b2[lane];
    float v[8], acc[8];
#pragma unroll
    for (int u = 0; u < 8; ++u) {
        v[u] = h[(size_t)(n0 + u) * 64 + lane];
        acc[u] = b1r;
    }
#pragma unroll 8
    for (int k = 0; k < 64; ++k) {
        float w = w1s[k * 64 + lane];
#pragma unroll
        for (int u = 0; u < 8; ++u) acc[u] = fmaf(rlf(v[u], k), w, acc[u]);
    }
#pragma unroll
    for (int u = 0; u < 8; ++u) {
        v[u] = fmaxf(acc[u], 0.f);
        acc[u] = b2r;
    }
#pragma unroll 8
    for (int k = 0; k < 64; ++k) {
        float w = w2s[k * 64 + lane];
#pragma unroll
        for (int u = 0; u < 8; ++u) acc[u] = fmaf(rlf(v[u], k), w, acc[u]);
    }
#pragma unroll
    for (int u = 0; u < 8; ++u)
        h[(size_t)(n0 + u) * 64 + lane] = fmaxf(acc[u], 0.f);
}

// K4: pair decoder, 8 pairs per wave. dw1 interleaved in LDS so that one
// ds_read_b128 per k gives lane j the 4 section weights (sum,prod,e1,e2)
// for (k,j); reused across 8 pairs -> LDS ops per pair drop 256 -> 8.
__global__ void __launch_bounds__(256) k4_pair(const float* __restrict__ h,
                        const int* __restrict__ qidx,
                        const float* __restrict__ dw1, const float* __restrict__ db1,
                        const float* __restrict__ dw2, const float* __restrict__ db2,
                        float* __restrict__ out, int numWaves) {
    __shared__ float W[256 * 64];  // W[(k*64+j)*4 + sec] = dw1[(sec*64+k)*64+j]
    int tid = threadIdx.x;
    for (int i = tid; i < 16384; i += 256) {
        int r = i >> 6, j = i & 63;
        int sec = r >> 6, k = r & 63;
        W[(((k << 6) + j) << 2) + sec] = dw1[i];
    }
    __syncthreads();
    const float4* W4 = (const float4*)W;
    int lane = tid & 63;
    float db1r = db1[lane];
    float dw2r = dw2[lane];
    float db2r = db2[0];
    int wid = (blockIdx.x * 256 + tid) >> 6;
    for (int t = wid; t < NPAIRS / 8; t += numWaves) {
        int p0 = t * 8;
        float e1[8], e2[8], acc[8];
#pragma unroll
        for (int u = 0; u < 8; ++u) {
            int i1 = qidx[p0 + u];
            int i2 = qidx[NPAIRS + p0 + u];
            e1[u] = h[(size_t)i1 * 64 + lane];
            e2[u] = h[(size_t)i2 * 64 + lane];
            acc[u] = db1r;
        }
#pragma unroll 4
        for (int k = 0; k < 64; ++k) {
            float4 w = W4[(k << 6) + lane];   // contiguous 1KB wave read
#pragma unroll
            for (int u = 0; u < 8; ++u) {
                float a = rlf(e1[u], k);
                float b = rlf(e2[u], k);
                acc[u] = fmaf(a + b, w.x, acc[u]);
                acc[u] = fmaf(a * b, w.y, acc[u]);
                acc[u] = fmaf(a,     w.z, acc[u]);
                acc[u] = fmaf(b,     w.w, acc[u]);
            }
        }
#pragma unroll
        for (int u = 0; u < 8; ++u) {
            float r = fmaxf(acc[u], 0.f) * dw2r;
#pragma unroll
            for (int off = 32; off >= 1; off >>= 1) r += __shfl_xor(r, off, 64);
            if (lane == 0) out[p0 + u] = r + db2r;
        }
    }
}

extern "C" void kernel_launch(void* const* d_in, const int* in_sizes, int n_in,
                              void* d_out, int out_size, void* d_ws, size_t ws_size,
                              hipStream_t stream) {
    const float* x    = (const float*)d_in[0];   // [N,64]
    const int*   eidx = (const int*)d_in[1];     // [2,E]
    const int*   qidx = (const int*)d_in[3];     // [2,P]
    const float* w1   = (const float*)d_in[4];
    const float* b1   = (const float*)d_in[5];
    const float* w2   = (const float*)d_in[6];
    const float* b2   = (const float*)d_in[7];
    const float* dw1  = (const float*)d_in[8];   // [256,64]
    const float* db1  = (const float*)d_in[9];
    const float* dw2  = (const float*)d_in[10];  // [64]
    const float* db2  = (const float*)d_in[11];  // [1]
    float* out = (float*)d_out;                  // [P]

    char* ws = (char*)d_ws;
    float* h0    = (float*)ws;
    int*   deg   = (int*)(ws + (size_t)N_NODES * FDIM * 4);
    int*   slots = (int*)(ws + (size_t)N_NODES * FDIM * 4 + (size_t)N_NODES * 4);

    const int* src = eidx;
    const int* dst = eidx + N_EDGES;

    k0_init<<<6250, 256, 0, stream>>>((const float4*)x, (float4*)h0, deg);
    k1_fill<<<6250, 256, 0, stream>>>(src, dst, x, h0, deg, slots);
    k2_agg<<<25000, 256, 0, stream>>>((const float4*)x, (float4*)h0, deg, slots);
    // K3: 8 nodes/wave, 12500 wave-tasks, 3125 blocks x 4 waves (exact)
    k3_mlp<<<3125, 256, 0, stream>>>(h0, w1, b1, w2, b2);
    // K4: 8 pairs/wave, 25000 wave-tasks, grid-stride over 512 blocks
    const int blocks4 = 512;
    k4_pair<<<blocks4, 256, 0, stream>>>(h0, qidx, dw1, db1, dw2, db2, out,
                                         blocks4 * 4);
}